// Round 3
// baseline (1894.876 us; speedup 1.0000x reference)
//
#include <hip/hip_runtime.h>
#include <hip/hip_bf16.h>

typedef __hip_bfloat16 bf16;

#define NN  4
#define CIN 96
#define C1  128
#define C2  144
#define HH  128
#define WW  256
#define HW  (HH * WW)

__device__ __forceinline__ float ldv(const float* p) { return *p; }
__device__ __forceinline__ float ldv(const bf16*  p) { return __bfloat162float(*p); }
__device__ __forceinline__ void  stv(float* p, float v) { *p = v; }
__device__ __forceinline__ void  stv(bf16*  p, float v) { *p = __float2bfloat16(v); }

// conv1: feat fp32 (N,96,H,W) -> hfeat (N,128,H,W), 3x3 pad1, +b1, LeakyReLU(0.1)
// Block = (n, co-group of 4, h); thread = w. Weights wave-uniform -> scalar loads.
template <typename TH>
__global__ __launch_bounds__(256) void conv1_kernel(
    const float* __restrict__ feat, const float* __restrict__ w1,
    const float* __restrict__ b1, TH* __restrict__ hfeat)
{
    const int w   = threadIdx.x;                    // 0..255
    const int h   = blockIdx.x % HH;
    const int cg  = (blockIdx.x / HH) % (C1 / 4);
    const int n   = blockIdx.x / (HH * (C1 / 4));
    const int co0 = cg * 4;

    float acc[4];
    #pragma unroll
    for (int j = 0; j < 4; ++j) acc[j] = b1[co0 + j];

    const float* fbase = feat + (size_t)n * CIN * HW;
    for (int ci = 0; ci < CIN; ++ci) {
        float fv[9];
        const float* fr = fbase + (size_t)ci * HW;
        #pragma unroll
        for (int kh = 0; kh < 3; ++kh) {
            const int hh = h + kh - 1;
            const bool hok = (hh >= 0) && (hh < HH);  // wave-uniform
            #pragma unroll
            for (int kw = 0; kw < 3; ++kw) {
                const int ww = w + kw - 1;
                float v = 0.f;
                if (hok && ww >= 0 && ww < WW) v = fr[hh * WW + ww];
                fv[kh * 3 + kw] = v;
            }
        }
        #pragma unroll
        for (int j = 0; j < 4; ++j) {
            const float* wp = w1 + ((size_t)(co0 + j) * CIN + ci) * 9;
            #pragma unroll
            for (int t = 0; t < 9; ++t) acc[j] += fv[t] * wp[t];
        }
    }
    #pragma unroll
    for (int j = 0; j < 4; ++j) {
        float a = acc[j];
        a = a > 0.f ? a : 0.1f * a;                  // LeakyReLU(0.1)
        stv(&hfeat[((size_t)(n * C1 + co0 + j) * HH + h) * WW + w], a);
    }
}

// conv2: hfeat (N,128,H,W) -> mask (N,144,H,W), 3x3 pad1, +b2, *0.25
template <typename TH, typename TM>
__global__ __launch_bounds__(256) void conv2_kernel(
    const TH* __restrict__ hfeat, const float* __restrict__ w2,
    const float* __restrict__ b2, TM* __restrict__ mask)
{
    const int w   = threadIdx.x;
    const int h   = blockIdx.x % HH;
    const int cg  = (blockIdx.x / HH) % (C2 / 4);
    const int n   = blockIdx.x / (HH * (C2 / 4));
    const int co0 = cg * 4;

    float acc[4];
    #pragma unroll
    for (int j = 0; j < 4; ++j) acc[j] = b2[co0 + j];

    const TH* fbase = hfeat + (size_t)n * C1 * HW;
    for (int ci = 0; ci < C1; ++ci) {
        float fv[9];
        const TH* fr = fbase + (size_t)ci * HW;
        #pragma unroll
        for (int kh = 0; kh < 3; ++kh) {
            const int hh = h + kh - 1;
            const bool hok = (hh >= 0) && (hh < HH);
            #pragma unroll
            for (int kw = 0; kw < 3; ++kw) {
                const int ww = w + kw - 1;
                float v = 0.f;
                if (hok && ww >= 0 && ww < WW) v = ldv(&fr[hh * WW + ww]);
                fv[kh * 3 + kw] = v;
            }
        }
        #pragma unroll
        for (int j = 0; j < 4; ++j) {
            const float* wp = w2 + ((size_t)(co0 + j) * C1 + ci) * 9;
            #pragma unroll
            for (int t = 0; t < 9; ++t) acc[j] += fv[t] * wp[t];
        }
    }
    #pragma unroll
    for (int j = 0; j < 4; ++j)
        stv(&mask[((size_t)(n * C2 + co0 + j) * HH + h) * WW + w], 0.25f * acc[j]);
}

// upsample: softmax over 9 neighbors per (a,b) cell, convex-combine 4*flow
// patches, scatter to (N,2,4H,4W) fp32. One block per (n,h); thread = w.
template <typename TM>
__global__ __launch_bounds__(256) void upsample_kernel(
    const float* __restrict__ flow, const TM* __restrict__ mask,
    float* __restrict__ out)
{
    const int w = threadIdx.x;
    const int h = blockIdx.x % HH;
    const int n = blockIdx.x / HH;

    float pf[2][9];
    #pragma unroll
    for (int c = 0; c < 2; ++c) {
        const float* fb = flow + (size_t)(n * 2 + c) * HW;
        #pragma unroll
        for (int i = 0; i < 3; ++i) {
            const int hh = h + i - 1;
            #pragma unroll
            for (int j = 0; j < 3; ++j) {
                const int ww = w + j - 1;
                float v = 0.f;
                if (hh >= 0 && hh < HH && ww >= 0 && ww < WW)
                    v = 4.f * fb[hh * WW + ww];
                pf[c][i * 3 + j] = v;
            }
        }
    }

    const TM* mb = mask + (size_t)n * C2 * HW + h * WW + w;
    const int H4 = 4 * HH, W4 = 4 * WW;

    #pragma unroll
    for (int ab = 0; ab < 16; ++ab) {
        // mask channel for (k, a, b) is k*16 + a*4 + b
        float v[9]; float mx = -1e30f;
        #pragma unroll
        for (int k = 0; k < 9; ++k) {
            v[k] = ldv(&mb[(size_t)(k * 16 + ab) * HW]);
            mx = fmaxf(mx, v[k]);
        }
        float s = 0.f;
        #pragma unroll
        for (int k = 0; k < 9; ++k) { v[k] = __expf(v[k] - mx); s += v[k]; }
        const float inv = 1.f / s;
        float o0 = 0.f, o1 = 0.f;
        #pragma unroll
        for (int k = 0; k < 9; ++k) { o0 += v[k] * pf[0][k]; o1 += v[k] * pf[1][k]; }
        const int a = ab >> 2, b = ab & 3;
        const size_t r = (size_t)(h * 4 + a) * W4 + (w * 4 + b);
        out[((size_t)(n * 2 + 0) * H4) * W4 + r] = o0 * inv;
        out[((size_t)(n * 2 + 1) * H4) * W4 + r] = o1 * inv;
    }
}

extern "C" void kernel_launch(void* const* d_in, const int* in_sizes, int n_in,
                              void* d_out, int out_size, void* d_ws, size_t ws_size,
                              hipStream_t stream)
{
    const float* flow = (const float*)d_in[0];
    const float* feat = (const float*)d_in[1];
    const float* w1   = (const float*)d_in[2];
    const float* b1   = (const float*)d_in[3];
    const float* w2   = (const float*)d_in[4];
    const float* b2   = (const float*)d_in[5];
    float* out = (float*)d_out;

    const size_t nh = (size_t)NN * C1 * HW;   // 16.78M elems
    const size_t nm = (size_t)NN * C2 * HW;   // 18.87M elems

    const int g1 = NN * (C1 / 4) * HH;
    const int g2 = NN * (C2 / 4) * HH;
    const int g3 = NN * HH;

    if (ws_size >= (nh + nm) * 4) {
        // fp32 hfeat + fp32 mask (142.6 MB)
        float* hfeat = (float*)d_ws;
        float* mask  = hfeat + nh;
        conv1_kernel<float><<<g1, 256, 0, stream>>>(feat, w1, b1, hfeat);
        conv2_kernel<float, float><<<g2, 256, 0, stream>>>(hfeat, w2, b2, mask);
        upsample_kernel<float><<<g3, 256, 0, stream>>>(flow, mask, out);
    } else if (ws_size >= nh * 4 + nm * 2) {
        // fp32 hfeat + bf16 mask (104.8 MB)
        float* hfeat = (float*)d_ws;
        bf16*  mask  = (bf16*)(hfeat + nh);
        conv1_kernel<float><<<g1, 256, 0, stream>>>(feat, w1, b1, hfeat);
        conv2_kernel<float, bf16><<<g2, 256, 0, stream>>>(hfeat, w2, b2, mask);
        upsample_kernel<bf16><<<g3, 256, 0, stream>>>(flow, mask, out);
    } else {
        // bf16 hfeat + bf16 mask (71.3 MB — footprint proven in R2)
        bf16* hfeat = (bf16*)d_ws;
        bf16* mask  = hfeat + nh;
        conv1_kernel<bf16><<<g1, 256, 0, stream>>>(feat, w1, b1, hfeat);
        conv2_kernel<bf16, bf16><<<g2, 256, 0, stream>>>(hfeat, w2, b2, mask);
        upsample_kernel<bf16><<<g3, 256, 0, stream>>>(flow, mask, out);
    }
}

// Round 4
// 358.216 us; speedup vs baseline: 5.2898x; 5.2898x over previous
//
#include <hip/hip_runtime.h>
#include <hip/hip_bf16.h>

#define NN  4
#define CIN 96
#define C1  128
#define C2  144
#define HH  128
#define WW  256
#define HW  (HH * WW)

typedef short bf16x8 __attribute__((ext_vector_type(8)));
typedef float f32x4  __attribute__((ext_vector_type(4)));

__device__ __forceinline__ short f2bs(float v) {
    __hip_bfloat16 b = __float2bfloat16(v);
    short s; __builtin_memcpy(&s, &b, 2); return s;
}

// ---------------------------------------------------------------------------
// pack weights (co,ci,kh,kw) fp32 -> [tap][co][ci] bf16 bits
// i = (co*cin + ci)*9 + tap
__global__ __launch_bounds__(256) void pack_w(const float* __restrict__ w,
                                              short* __restrict__ wb,
                                              int cout, int cin)
{
    int i = blockIdx.x * 256 + threadIdx.x;
    if (i >= cout * cin * 9) return;
    int tap = i % 9;
    int t   = i / 9;
    int ci  = t % cin;
    int co  = t / cin;
    wb[(tap * cout + co) * cin + ci] = f2bs(w[i]);
}

// ---------------------------------------------------------------------------
// conv1 implicit-GEMM MFMA: feat fp32 NCHW (N,96,H,W) -> hfeat bf16 NHWC
// (n,h,w,c1). Block = (n,h); 4 waves split w into 64-wide strips; each wave:
// 4 m-tiles (16 w) x 8 co-tiles (16 co), K = 96 in 3 chunks of 32.
// LDS tile: [3 rows][258 w (halo)][32 ci + 8 pad] bf16.
__global__ __launch_bounds__(256, 2) void conv1_mfma(
    const float* __restrict__ feat, const short* __restrict__ w1b,
    const float* __restrict__ b1, short* __restrict__ hfeat)
{
    __shared__ short lds[3 * 258 * 40];           // 61,920 B
    const int tid  = threadIdx.x;
    const int h    = blockIdx.x & (HH - 1);
    const int n    = blockIdx.x >> 7;
    const int lane = tid & 63;
    const int wave = tid >> 6;
    const int quad = lane >> 4;
    const int col  = lane & 15;
    const int w0   = wave * 64;

    f32x4 acc[4][8];
    #pragma unroll
    for (int mt = 0; mt < 4; ++mt)
        #pragma unroll
        for (int ct = 0; ct < 8; ++ct)
            #pragma unroll
            for (int r = 0; r < 4; ++r) acc[mt][ct][r] = 0.f;

    for (int kci = 0; kci < 3; ++kci) {
        const int kc = kci * 32;
        if (kci) __syncthreads();
        // ---- stage: rows h-1..h+1, chunk of 32 ci, fp32 -> bf16 ----
        for (int rc = 0; rc < 96; ++rc) {
            const int row = rc >> 5, ci = rc & 31;
            const int hh = h + row - 1;
            float v = 0.f;
            if (hh >= 0 && hh < HH)
                v = feat[(((size_t)n * CIN + kc + ci) * HH + hh) * WW + tid];
            lds[(row * 258 + tid + 1) * 40 + ci] = f2bs(v);
            if (tid < 2)  // w halo = 0
                lds[(row * 258 + (tid == 0 ? 0 : 257)) * 40 + ci] = 0;
        }
        __syncthreads();
        // ---- MFMA over 9 taps ----
        #pragma unroll
        for (int tap = 0; tap < 9; ++tap) {
            const int dh = tap / 3, dw = tap % 3;
            bf16x8 af[4];
            #pragma unroll
            for (int mt = 0; mt < 4; ++mt) {
                const int wi = w0 + mt * 16 + col + dw;   // 0..257
                af[mt] = *(const bf16x8*)&lds[(dh * 258 + wi) * 40 + quad * 8];
            }
            #pragma unroll
            for (int ct = 0; ct < 8; ++ct) {
                const bf16x8 bfr = *(const bf16x8*)
                    &w1b[((tap * C1 + ct * 16 + col) * CIN) + kc + quad * 8];
                #pragma unroll
                for (int mt = 0; mt < 4; ++mt)
                    acc[mt][ct] = __builtin_amdgcn_mfma_f32_16x16x32_bf16(
                        af[mt], bfr, acc[mt][ct], 0, 0, 0);
            }
        }
    }

    // ---- epilogue: +bias, LeakyReLU(0.1), write NHWC bf16 ----
    float bias[8];
    #pragma unroll
    for (int ct = 0; ct < 8; ++ct) bias[ct] = b1[ct * 16 + col];
    const size_t obase = ((size_t)(n * HH + h) * WW) * C1;
    #pragma unroll
    for (int mt = 0; mt < 4; ++mt)
        #pragma unroll
        for (int r = 0; r < 4; ++r) {
            const int w = w0 + mt * 16 + quad * 4 + r;
            const size_t ro = obase + (size_t)w * C1;
            #pragma unroll
            for (int ct = 0; ct < 8; ++ct) {
                float a = acc[mt][ct][r] + bias[ct];
                a = a > 0.f ? a : 0.1f * a;
                hfeat[ro + ct * 16 + col] = f2bs(a);
            }
        }
}

// ---------------------------------------------------------------------------
// conv2 implicit-GEMM MFMA + fused bias/0.25/softmax-9/convex-upsample.
// hfeat bf16 NHWC -> out fp32 (N,2,4H,4W). Block = (n,h), K = 128 in 4
// chunks. Lane with col=ab holds all 9 logit channels (k*16+ab) for its
// 16 pixels -> softmax entirely in registers.
__global__ __launch_bounds__(256, 2) void conv2_fused(
    const short* __restrict__ hfeat, const short* __restrict__ w2b,
    const float* __restrict__ b2, const float* __restrict__ flow,
    float* __restrict__ out)
{
    __shared__ short lds[3 * 258 * 40];
    const int tid  = threadIdx.x;
    const int h    = blockIdx.x & (HH - 1);
    const int n    = blockIdx.x >> 7;
    const int lane = tid & 63;
    const int wave = tid >> 6;
    const int quad = lane >> 4;
    const int col  = lane & 15;
    const int w0   = wave * 64;

    f32x4 acc[4][9];
    #pragma unroll
    for (int mt = 0; mt < 4; ++mt)
        #pragma unroll
        for (int ct = 0; ct < 9; ++ct)
            #pragma unroll
            for (int r = 0; r < 4; ++r) acc[mt][ct][r] = 0.f;

    for (int kci = 0; kci < 4; ++kci) {
        const int kc = kci * 32;
        if (kci) __syncthreads();
        // ---- stage: 16B vector loads from NHWC hfeat ----
        for (int s = tid; s < 3 * 258 * 4; s += 256) {
            const int cig = s & 3;
            const int w_  = (s >> 2) % 258;
            const int row = (s >> 2) / 258;
            const int hh = h + row - 1, gw = w_ - 1;
            bf16x8 v;
            #pragma unroll
            for (int j = 0; j < 8; ++j) v[j] = 0;
            if (hh >= 0 && hh < HH && gw >= 0 && gw < WW)
                v = *(const bf16x8*)
                    &hfeat[(((size_t)n * HH + hh) * WW + gw) * C1 + kc + cig * 8];
            *(bf16x8*)&lds[(row * 258 + w_) * 40 + cig * 8] = v;
        }
        __syncthreads();
        #pragma unroll
        for (int tap = 0; tap < 9; ++tap) {
            const int dh = tap / 3, dw = tap % 3;
            bf16x8 af[4];
            #pragma unroll
            for (int mt = 0; mt < 4; ++mt) {
                const int wi = w0 + mt * 16 + col + dw;
                af[mt] = *(const bf16x8*)&lds[(dh * 258 + wi) * 40 + quad * 8];
            }
            #pragma unroll
            for (int ct = 0; ct < 9; ++ct) {
                const bf16x8 bfr = *(const bf16x8*)
                    &w2b[((tap * C2 + ct * 16 + col) * C1) + kc + quad * 8];
                #pragma unroll
                for (int mt = 0; mt < 4; ++mt)
                    acc[mt][ct] = __builtin_amdgcn_mfma_f32_16x16x32_bf16(
                        af[mt], bfr, acc[mt][ct], 0, 0, 0);
            }
        }
    }

    // ---- fused epilogue: softmax over 9 taps, combine 4*flow, upsample ----
    const int a_ = col >> 2, b_ = col & 3;
    float bias[9];
    #pragma unroll
    for (int k = 0; k < 9; ++k) bias[k] = b2[k * 16 + col];
    const int H4 = 4 * HH, W4 = 4 * WW;

    #pragma unroll
    for (int mt = 0; mt < 4; ++mt)
        #pragma unroll
        for (int r = 0; r < 4; ++r) {
            const int w = w0 + mt * 16 + quad * 4 + r;
            float v[9], mx = -1e30f;
            #pragma unroll
            for (int k = 0; k < 9; ++k) {
                v[k] = 0.25f * (acc[mt][k][r] + bias[k]);
                mx = fmaxf(mx, v[k]);
            }
            float s = 0.f;
            #pragma unroll
            for (int k = 0; k < 9; ++k) { v[k] = __expf(v[k] - mx); s += v[k]; }
            const float inv = 4.f / s;          // folds the 4*flow scale
            float o0 = 0.f, o1 = 0.f;
            #pragma unroll
            for (int ki = 0; ki < 3; ++ki) {
                const int hh = h + ki - 1;
                #pragma unroll
                for (int kj = 0; kj < 3; ++kj) {
                    const int ww = w + kj - 1;
                    if (hh >= 0 && hh < HH && ww >= 0 && ww < WW) {
                        const float wgt = v[ki * 3 + kj];
                        o0 += wgt * flow[(((size_t)n * 2 + 0) * HH + hh) * WW + ww];
                        o1 += wgt * flow[(((size_t)n * 2 + 1) * HH + hh) * WW + ww];
                    }
                }
            }
            const size_t o = ((size_t)(n * 2) * H4 + 4 * h + a_) * W4 + 4 * w + b_;
            out[o] = o0 * inv;
            out[o + (size_t)H4 * W4] = o1 * inv;
        }
}

// ---------------------------------------------------------------------------
extern "C" void kernel_launch(void* const* d_in, const int* in_sizes, int n_in,
                              void* d_out, int out_size, void* d_ws, size_t ws_size,
                              hipStream_t stream)
{
    const float* flow = (const float*)d_in[0];
    const float* feat = (const float*)d_in[1];
    const float* w1   = (const float*)d_in[2];
    const float* b1   = (const float*)d_in[3];
    const float* w2   = (const float*)d_in[4];
    const float* b2   = (const float*)d_in[5];
    float* out = (float*)d_out;

    // ws: hfeat bf16 NHWC (33.55 MB) + w1b (0.22 MB) + w2b (0.33 MB)
    short* hfeat = (short*)d_ws;
    short* w1b   = hfeat + (size_t)NN * HH * WW * C1;   // 16,777,216 elems
    short* w2b   = w1b + (size_t)9 * C1 * CIN;          // 110,592 elems

    pack_w<<<(9 * C1 * CIN) / 256, 256, 0, stream>>>(w1, w1b, C1, CIN);
    pack_w<<<(9 * C2 * C1) / 256, 256, 0, stream>>>(w2, w2b, C2, C1);
    conv1_mfma<<<NN * HH, 256, 0, stream>>>(feat, w1b, b1, hfeat);
    conv2_fused<<<NN * HH, 256, 0, stream>>>(hfeat, w2b, b2, flow, out);
}

// Round 6
// 354.792 us; speedup vs baseline: 5.3408x; 1.0097x over previous
//
#include <hip/hip_runtime.h>
#include <hip/hip_bf16.h>

#define NN  4
#define CIN 96
#define C1  128
#define C2  144
#define HH  128
#define WW  256

typedef short bf16x8 __attribute__((ext_vector_type(8)));
typedef float f32x4  __attribute__((ext_vector_type(4)));
typedef unsigned int u32x4 __attribute__((ext_vector_type(4)));

__device__ __forceinline__ short f2bs(float v) {
    __hip_bfloat16 b = __float2bfloat16(v);
    short s; __builtin_memcpy(&s, &b, 2); return s;
}

// ---------------------------------------------------------------------------
// NCHW fp32 -> NHWC bf16 transpose of feat. Block = (n,h); LDS pair-packed,
// conflict-free both phases (row stride 258 dwords).
__global__ __launch_bounds__(256) void transpose_feat(
    const float* __restrict__ feat, short* __restrict__ featT)
{
    __shared__ unsigned int lds[48 * 258];        // 49.5 KB
    const int tid = threadIdx.x;
    const int h = blockIdx.x & (HH - 1);
    const int n = blockIdx.x >> 7;

    #pragma unroll 4
    for (int cp = 0; cp < 48; ++cp) {             // channel pairs
        float v0 = feat[(((size_t)n * CIN + 2 * cp    ) * HH + h) * WW + tid];
        float v1 = feat[(((size_t)n * CIN + 2 * cp + 1) * HH + h) * WW + tid];
        unsigned int p = (unsigned int)(unsigned short)f2bs(v0)
                       | ((unsigned int)(unsigned short)f2bs(v1) << 16);
        lds[cp * 258 + tid] = p;
    }
    __syncthreads();
    const size_t pbase = ((size_t)(n * HH + h) * WW + tid) * CIN;
    #pragma unroll
    for (int rec = 0; rec < 12; ++rec) {          // 12 x 16B per pixel record
        u32x4 v;
        #pragma unroll
        for (int k = 0; k < 4; ++k) v[k] = lds[(rec * 4 + k) * 258 + tid];
        *(u32x4*)&featT[pbase + rec * 8] = v;
    }
}

// ---------------------------------------------------------------------------
// Pack weights (co,ci,3,3) fp32 -> B-fragment-ordered bf16:
// wp[(((kci*9+tap)*nct + ct)*64 + lane)*8 + j], co=ct*16+col, ci=kci*32+quad*8+j
// -> each B-frag load is 64 lanes x contiguous 16B (1 KB coalesced).
__global__ __launch_bounds__(256) void pack_wB(
    const float* __restrict__ w, short* __restrict__ wp,
    int cin, int nct, int total)
{
    int i = blockIdx.x * 256 + threadIdx.x;
    if (i >= total) return;
    const int j    = i & 7;
    const int col  = (i >> 3) & 15;
    const int quad = (i >> 7) & 3;
    int t = i >> 9;                               // (kci*9+tap)*nct + ct
    const int ct  = t % nct;  t /= nct;
    const int tap = t % 9;
    const int kci = t / 9;
    const int co = ct * 16 + col;
    const int ci = kci * 32 + quad * 8 + j;
    wp[i] = f2bs(w[((size_t)co * cin + ci) * 9 + tap]);
}

// ---------------------------------------------------------------------------
// conv1: featT bf16 NHWC -> hfeat bf16 NHWC. LDS-free, barrier-free MFMA
// stream: A-frag = direct 16B global load (L1/L2-hot), B-frag = coalesced
// packed weights. Block = (n,h,w-half); wave = 32 px; OOB taps skipped.
__global__ __launch_bounds__(256, 3) void conv1_mfma(
    const short* __restrict__ featT, const short* __restrict__ w1p,
    const float* __restrict__ b1, short* __restrict__ hfeat)
{
    const int tid  = threadIdx.x;
    const int wb   = blockIdx.x & 1;
    const int h    = (blockIdx.x >> 1) & (HH - 1);
    const int n    = blockIdx.x >> 8;
    const int lane = tid & 63, wave = tid >> 6;
    const int quad = lane >> 4, col = lane & 15;
    const int wp0  = wb * 128 + wave * 32;

    f32x4 acc[2][8];
    #pragma unroll
    for (int mt = 0; mt < 2; ++mt)
        #pragma unroll
        for (int ct = 0; ct < 8; ++ct)
            #pragma unroll
            for (int r = 0; r < 4; ++r) acc[mt][ct][r] = 0.f;

    for (int kci = 0; kci < 3; ++kci) {
        #pragma unroll
        for (int tap = 0; tap < 9; ++tap) {
            const int dh = tap / 3, dw = tap % 3;
            const int hh = h + dh - 1;
            if (hh < 0 || hh >= HH) continue;     // wave-uniform; A rows = 0
            const size_t rbase = ((size_t)(n * HH + hh)) * WW;
            bf16x8 af[2];
            #pragma unroll
            for (int mt = 0; mt < 2; ++mt) {
                const int gw = wp0 + mt * 16 + col + dw - 1;
                const bool ok = (unsigned)gw < (unsigned)WW;
                bf16x8 a = {};
                if (ok)
                    a = *(const bf16x8*)
                        &featT[(rbase + gw) * CIN + kci * 32 + quad * 8];
                af[mt] = a;
            }
            const short* bp = w1p + (((size_t)(kci * 9 + tap) * 8) << 9) + (lane << 3);
            #pragma unroll
            for (int ct = 0; ct < 8; ++ct) {
                const bf16x8 bfr = *(const bf16x8*)(bp + ((size_t)ct << 9));
                acc[0][ct] = __builtin_amdgcn_mfma_f32_16x16x32_bf16(af[0], bfr, acc[0][ct], 0, 0, 0);
                acc[1][ct] = __builtin_amdgcn_mfma_f32_16x16x32_bf16(af[1], bfr, acc[1][ct], 0, 0, 0);
            }
        }
    }

    float bias[8];
    #pragma unroll
    for (int ct = 0; ct < 8; ++ct) bias[ct] = b1[ct * 16 + col];
    #pragma unroll
    for (int mt = 0; mt < 2; ++mt)
        #pragma unroll
        for (int r = 0; r < 4; ++r) {
            const int w = wp0 + mt * 16 + quad * 4 + r;
            const size_t ro = ((size_t)(n * HH + h) * WW + w) * C1;
            #pragma unroll
            for (int ct = 0; ct < 8; ++ct) {
                float a = acc[mt][ct][r] + bias[ct];
                a = a > 0.f ? a : 0.1f * a;       // LeakyReLU(0.1)
                hfeat[ro + ct * 16 + col] = f2bs(a);
            }
        }
}

// ---------------------------------------------------------------------------
// conv2 + fused bias/0.25/softmax-9/convex-upsample. Same LDS-free structure.
// Lane col=ab holds all 9 logits for its pixels -> softmax in registers.
__global__ __launch_bounds__(256, 3) void conv2_fused(
    const short* __restrict__ hfeat, const short* __restrict__ w2p,
    const float* __restrict__ b2, const float* __restrict__ flow,
    float* __restrict__ out)
{
    const int tid  = threadIdx.x;
    const int wb   = blockIdx.x & 1;
    const int h    = (blockIdx.x >> 1) & (HH - 1);
    const int n    = blockIdx.x >> 8;
    const int lane = tid & 63, wave = tid >> 6;
    const int quad = lane >> 4, col = lane & 15;
    const int wp0  = wb * 128 + wave * 32;

    f32x4 acc[2][9];
    #pragma unroll
    for (int mt = 0; mt < 2; ++mt)
        #pragma unroll
        for (int ct = 0; ct < 9; ++ct)
            #pragma unroll
            for (int r = 0; r < 4; ++r) acc[mt][ct][r] = 0.f;

    for (int kci = 0; kci < 4; ++kci) {
        #pragma unroll
        for (int tap = 0; tap < 9; ++tap) {
            const int dh = tap / 3, dw = tap % 3;
            const int hh = h + dh - 1;
            if (hh < 0 || hh >= HH) continue;
            const size_t rbase = ((size_t)(n * HH + hh)) * WW;
            bf16x8 af[2];
            #pragma unroll
            for (int mt = 0; mt < 2; ++mt) {
                const int gw = wp0 + mt * 16 + col + dw - 1;
                const bool ok = (unsigned)gw < (unsigned)WW;
                bf16x8 a = {};
                if (ok)
                    a = *(const bf16x8*)
                        &hfeat[(rbase + gw) * C1 + kci * 32 + quad * 8];
                af[mt] = a;
            }
            const short* bp = w2p + (((size_t)(kci * 9 + tap) * 9) << 9) + (lane << 3);
            #pragma unroll
            for (int ct = 0; ct < 9; ++ct) {
                const bf16x8 bfr = *(const bf16x8*)(bp + ((size_t)ct << 9));
                acc[0][ct] = __builtin_amdgcn_mfma_f32_16x16x32_bf16(af[0], bfr, acc[0][ct], 0, 0, 0);
                acc[1][ct] = __builtin_amdgcn_mfma_f32_16x16x32_bf16(af[1], bfr, acc[1][ct], 0, 0, 0);
            }
        }
    }

    const int a_ = col >> 2, b_ = col & 3;
    float bias[9];
    #pragma unroll
    for (int k = 0; k < 9; ++k) bias[k] = b2[k * 16 + col];
    const int H4 = 4 * HH, W4 = 4 * WW;

    #pragma unroll
    for (int mt = 0; mt < 2; ++mt)
        #pragma unroll
        for (int r = 0; r < 4; ++r) {
            const int w = wp0 + mt * 16 + quad * 4 + r;
            float v[9], mx = -1e30f;
            #pragma unroll
            for (int k = 0; k < 9; ++k) {
                v[k] = 0.25f * (acc[mt][k][r] + bias[k]);
                mx = fmaxf(mx, v[k]);
            }
            float s = 0.f;
            #pragma unroll
            for (int k = 0; k < 9; ++k) { v[k] = __expf(v[k] - mx); s += v[k]; }
            const float inv = 4.f / s;            // folds the 4*flow scale
            float o0 = 0.f, o1 = 0.f;
            #pragma unroll
            for (int ki = 0; ki < 3; ++ki) {
                const int hh = h + ki - 1;
                #pragma unroll
                for (int kj = 0; kj < 3; ++kj) {
                    const int ww = w + kj - 1;
                    if (hh >= 0 && hh < HH && ww >= 0 && ww < WW) {
                        const float wgt = v[ki * 3 + kj];
                        o0 += wgt * flow[(((size_t)n * 2 + 0) * HH + hh) * WW + ww];
                        o1 += wgt * flow[(((size_t)n * 2 + 1) * HH + hh) * WW + ww];
                    }
                }
            }
            const size_t o = ((size_t)(n * 2) * H4 + 4 * h + a_) * W4 + 4 * w + b_;
            out[o] = o0 * inv;
            out[o + (size_t)H4 * W4] = o1 * inv;
        }
}

// ---------------------------------------------------------------------------
extern "C" void kernel_launch(void* const* d_in, const int* in_sizes, int n_in,
                              void* d_out, int out_size, void* d_ws, size_t ws_size,
                              hipStream_t stream)
{
    const float* flow = (const float*)d_in[0];
    const float* feat = (const float*)d_in[1];
    const float* w1   = (const float*)d_in[2];
    const float* b1   = (const float*)d_in[3];
    const float* w2   = (const float*)d_in[4];
    const float* b2   = (const float*)d_in[5];
    float* out = (float*)d_out;

    // ws: featT 25.2 MB + hfeat 33.6 MB + w1p 0.22 MB + w2p 0.33 MB = 59.3 MB
    short* featT = (short*)d_ws;
    short* hfeat = featT + (size_t)NN * HH * WW * CIN;   // 12,582,912
    short* w1p   = hfeat + (size_t)NN * HH * WW * C1;    // 16,777,216
    short* w2p   = w1p + (size_t)3 * 9 * 8 * 512;        // 110,592

    const int tot1 = 3 * 9 * 8 * 512;                    // 110,592
    const int tot2 = 4 * 9 * 9 * 512;                    // 165,888

    transpose_feat<<<NN * HH, 256, 0, stream>>>(feat, featT);
    pack_wB<<<(tot1 + 255) / 256, 256, 0, stream>>>(w1, w1p, CIN, 8, tot1);
    pack_wB<<<(tot2 + 255) / 256, 256, 0, stream>>>(w2, w2p, C1, 9, tot2);
    conv1_mfma<<<NN * HH * 2, 256, 0, stream>>>(featT, w1p, b1, hfeat);
    conv2_fused<<<NN * HH * 2, 256, 0, stream>>>(hfeat, w2p, b2, flow, out);
}

// Round 7
// 236.720 us; speedup vs baseline: 8.0047x; 1.4988x over previous
//
#include <hip/hip_runtime.h>
#include <hip/hip_bf16.h>

#define NN  4
#define CIN 96
#define C1  128
#define C2  144
#define HH  128
#define WW  256

typedef short bf16x8 __attribute__((ext_vector_type(8)));
typedef float f32x4  __attribute__((ext_vector_type(4)));
typedef unsigned int u32x4 __attribute__((ext_vector_type(4)));

__device__ __forceinline__ short f2bs(float v) {
    __hip_bfloat16 b = __float2bfloat16(v);
    short s; __builtin_memcpy(&s, &b, 2); return s;
}

// ---------------------------------------------------------------------------
// NCHW fp32 -> NHWC bf16 transpose of feat. Block = (n,h); LDS pair-packed,
// conflict-free both phases (row stride 258 dwords).
__global__ __launch_bounds__(256) void transpose_feat(
    const float* __restrict__ feat, short* __restrict__ featT)
{
    __shared__ unsigned int lds[48 * 258];        // 49.5 KB
    const int tid = threadIdx.x;
    const int h = blockIdx.x & (HH - 1);
    const int n = blockIdx.x >> 7;

    #pragma unroll 4
    for (int cp = 0; cp < 48; ++cp) {             // channel pairs
        float v0 = feat[(((size_t)n * CIN + 2 * cp    ) * HH + h) * WW + tid];
        float v1 = feat[(((size_t)n * CIN + 2 * cp + 1) * HH + h) * WW + tid];
        unsigned int p = (unsigned int)(unsigned short)f2bs(v0)
                       | ((unsigned int)(unsigned short)f2bs(v1) << 16);
        lds[cp * 258 + tid] = p;
    }
    __syncthreads();
    const size_t pbase = ((size_t)(n * HH + h) * WW + tid) * CIN;
    #pragma unroll
    for (int rec = 0; rec < 12; ++rec) {          // 12 x 16B per pixel record
        u32x4 v;
        #pragma unroll
        for (int k = 0; k < 4; ++k) v[k] = lds[(rec * 4 + k) * 258 + tid];
        *(u32x4*)&featT[pbase + rec * 8] = v;
    }
}

// ---------------------------------------------------------------------------
// Pack weights (co,ci,3,3) fp32 -> B-fragment-ordered bf16:
// wp[(((kci*9+tap)*nct + ct)*64 + lane)*8 + j], co=ct*16+col, ci=kci*32+quad*8+j
__global__ __launch_bounds__(256) void pack_wB(
    const float* __restrict__ w, short* __restrict__ wp,
    int cin, int nct, int total)
{
    int i = blockIdx.x * 256 + threadIdx.x;
    if (i >= total) return;
    const int j    = i & 7;
    const int col  = (i >> 3) & 15;
    const int quad = (i >> 7) & 3;
    int t = i >> 9;                               // (kci*9+tap)*nct + ct
    const int ct  = t % nct;  t /= nct;
    const int tap = t % 9;
    const int kci = t / 9;
    const int co = ct * 16 + col;
    const int ci = kci * 32 + quad * 8 + j;
    wp[i] = f2bs(w[((size_t)co * cin + ci) * 9 + tap]);
}

// ---------------------------------------------------------------------------
// conv1: featT bf16 NHWC -> hfeat bf16 NHWC. Block = (n,h), 512 thr / 8 waves,
// each wave a 32-px strip. Per 32-ci chunk: stage 3x258-px window (64B/px)
// into LDS cooperatively, then 9 taps of ds_read_b128 A-frags + MFMA.
__global__ __launch_bounds__(512, 2) void conv1_mfma(
    const short* __restrict__ featT, const short* __restrict__ w1p,
    const float* __restrict__ b1, short* __restrict__ hfeat)
{
    __shared__ short lds[3 * 258 * 32];           // 49,536 B
    const int tid  = threadIdx.x;
    const int h    = blockIdx.x & (HH - 1);
    const int n    = blockIdx.x >> 7;
    const int lane = tid & 63, wave = tid >> 6;
    const int quad = lane >> 4, col = lane & 15;
    const int wp0  = wave * 32;

    f32x4 acc[2][8];
    #pragma unroll
    for (int mt = 0; mt < 2; ++mt)
        #pragma unroll
        for (int ct = 0; ct < 8; ++ct)
            #pragma unroll
            for (int r = 0; r < 4; ++r) acc[mt][ct][r] = 0.f;

    for (int kci = 0; kci < 3; ++kci) {
        if (kci) __syncthreads();
        // ---- stage window: rows h-1..h+1, px -1..256, 32 ci (16B x 4) ----
        for (int s = tid; s < 3 * 258 * 4; s += 512) {
            const int cig = s & 3;
            const int px  = (s >> 2) % 258;
            const int row = (s >> 2) / 258;
            const int hh = h + row - 1, gw = px - 1;
            bf16x8 v = {};
            if (hh >= 0 && hh < HH && gw >= 0 && gw < WW)
                v = *(const bf16x8*)
                    &featT[(((size_t)n * HH + hh) * WW + gw) * CIN + kci * 32 + cig * 8];
            *(bf16x8*)&lds[((row * 258 + px) << 5) + cig * 8] = v;
        }
        __syncthreads();
        // ---- 9 taps of MFMA from LDS ----
        #pragma unroll
        for (int tap = 0; tap < 9; ++tap) {
            const int dh = tap / 3, dw = tap % 3;
            bf16x8 af[2];
            #pragma unroll
            for (int mt = 0; mt < 2; ++mt)
                af[mt] = *(const bf16x8*)
                    &lds[((dh * 258 + wp0 + mt * 16 + col + dw) << 5) + quad * 8];
            const short* bp = w1p + (((size_t)(kci * 9 + tap) * 8) << 9) + (lane << 3);
            #pragma unroll
            for (int ct = 0; ct < 8; ++ct) {
                const bf16x8 bfr = *(const bf16x8*)(bp + ((size_t)ct << 9));
                acc[0][ct] = __builtin_amdgcn_mfma_f32_16x16x32_bf16(af[0], bfr, acc[0][ct], 0, 0, 0);
                acc[1][ct] = __builtin_amdgcn_mfma_f32_16x16x32_bf16(af[1], bfr, acc[1][ct], 0, 0, 0);
            }
        }
    }

    float bias[8];
    #pragma unroll
    for (int ct = 0; ct < 8; ++ct) bias[ct] = b1[ct * 16 + col];
    #pragma unroll
    for (int mt = 0; mt < 2; ++mt)
        #pragma unroll
        for (int r = 0; r < 4; ++r) {
            const int w = wp0 + mt * 16 + quad * 4 + r;
            const size_t ro = ((size_t)(n * HH + h) * WW + w) * C1;
            #pragma unroll
            for (int ct = 0; ct < 8; ++ct) {
                float a = acc[mt][ct][r] + bias[ct];
                a = a > 0.f ? a : 0.1f * a;       // LeakyReLU(0.1)
                hfeat[ro + ct * 16 + col] = f2bs(a);
            }
        }
}

// ---------------------------------------------------------------------------
// conv2 + fused bias/0.25/softmax-9/convex-upsample. Same staged structure,
// K = 128 in 4 chunks. Lane col=ab holds all 9 logits -> softmax in regs.
__global__ __launch_bounds__(512, 2) void conv2_fused(
    const short* __restrict__ hfeat, const short* __restrict__ w2p,
    const float* __restrict__ b2, const float* __restrict__ flow,
    float* __restrict__ out)
{
    __shared__ short lds[3 * 258 * 32];           // 49,536 B
    const int tid  = threadIdx.x;
    const int h    = blockIdx.x & (HH - 1);
    const int n    = blockIdx.x >> 7;
    const int lane = tid & 63, wave = tid >> 6;
    const int quad = lane >> 4, col = lane & 15;
    const int wp0  = wave * 32;

    f32x4 acc[2][9];
    #pragma unroll
    for (int mt = 0; mt < 2; ++mt)
        #pragma unroll
        for (int ct = 0; ct < 9; ++ct)
            #pragma unroll
            for (int r = 0; r < 4; ++r) acc[mt][ct][r] = 0.f;

    for (int kci = 0; kci < 4; ++kci) {
        if (kci) __syncthreads();
        for (int s = tid; s < 3 * 258 * 4; s += 512) {
            const int cig = s & 3;
            const int px  = (s >> 2) % 258;
            const int row = (s >> 2) / 258;
            const int hh = h + row - 1, gw = px - 1;
            bf16x8 v = {};
            if (hh >= 0 && hh < HH && gw >= 0 && gw < WW)
                v = *(const bf16x8*)
                    &hfeat[(((size_t)n * HH + hh) * WW + gw) * C1 + kci * 32 + cig * 8];
            *(bf16x8*)&lds[((row * 258 + px) << 5) + cig * 8] = v;
        }
        __syncthreads();
        #pragma unroll
        for (int tap = 0; tap < 9; ++tap) {
            const int dh = tap / 3, dw = tap % 3;
            bf16x8 af[2];
            #pragma unroll
            for (int mt = 0; mt < 2; ++mt)
                af[mt] = *(const bf16x8*)
                    &lds[((dh * 258 + wp0 + mt * 16 + col + dw) << 5) + quad * 8];
            const short* bp = w2p + (((size_t)(kci * 9 + tap) * 9) << 9) + (lane << 3);
            #pragma unroll
            for (int ct = 0; ct < 9; ++ct) {
                const bf16x8 bfr = *(const bf16x8*)(bp + ((size_t)ct << 9));
                acc[0][ct] = __builtin_amdgcn_mfma_f32_16x16x32_bf16(af[0], bfr, acc[0][ct], 0, 0, 0);
                acc[1][ct] = __builtin_amdgcn_mfma_f32_16x16x32_bf16(af[1], bfr, acc[1][ct], 0, 0, 0);
            }
        }
    }

    const int a_ = col >> 2, b_ = col & 3;
    float bias[9];
    #pragma unroll
    for (int k = 0; k < 9; ++k) bias[k] = b2[k * 16 + col];
    const int H4 = 4 * HH, W4 = 4 * WW;

    #pragma unroll
    for (int mt = 0; mt < 2; ++mt)
        #pragma unroll
        for (int r = 0; r < 4; ++r) {
            const int w = wp0 + mt * 16 + quad * 4 + r;
            float v[9], mx = -1e30f;
            #pragma unroll
            for (int k = 0; k < 9; ++k) {
                v[k] = 0.25f * (acc[mt][k][r] + bias[k]);
                mx = fmaxf(mx, v[k]);
            }
            float s = 0.f;
            #pragma unroll
            for (int k = 0; k < 9; ++k) { v[k] = __expf(v[k] - mx); s += v[k]; }
            const float inv = 4.f / s;            // folds the 4*flow scale
            float o0 = 0.f, o1 = 0.f;
            #pragma unroll
            for (int ki = 0; ki < 3; ++ki) {
                const int hh = h + ki - 1;
                #pragma unroll
                for (int kj = 0; kj < 3; ++kj) {
                    const int ww = w + kj - 1;
                    if (hh >= 0 && hh < HH && ww >= 0 && ww < WW) {
                        const float wgt = v[ki * 3 + kj];
                        o0 += wgt * flow[(((size_t)n * 2 + 0) * HH + hh) * WW + ww];
                        o1 += wgt * flow[(((size_t)n * 2 + 1) * HH + hh) * WW + ww];
                    }
                }
            }
            const size_t o = ((size_t)(n * 2) * H4 + 4 * h + a_) * W4 + 4 * w + b_;
            out[o] = o0 * inv;
            out[o + (size_t)H4 * W4] = o1 * inv;
        }
}

// ---------------------------------------------------------------------------
extern "C" void kernel_launch(void* const* d_in, const int* in_sizes, int n_in,
                              void* d_out, int out_size, void* d_ws, size_t ws_size,
                              hipStream_t stream)
{
    const float* flow = (const float*)d_in[0];
    const float* feat = (const float*)d_in[1];
    const float* w1   = (const float*)d_in[2];
    const float* b1   = (const float*)d_in[3];
    const float* w2   = (const float*)d_in[4];
    const float* b2   = (const float*)d_in[5];
    float* out = (float*)d_out;

    // ws: featT 25.2 MB + hfeat 33.6 MB + w1p 0.22 MB + w2p 0.33 MB
    short* featT = (short*)d_ws;
    short* hfeat = featT + (size_t)NN * HH * WW * CIN;   // 12,582,912
    short* w1p   = hfeat + (size_t)NN * HH * WW * C1;    // 16,777,216
    short* w2p   = w1p + (size_t)3 * 9 * 8 * 512;        // 110,592

    const int tot1 = 3 * 9 * 8 * 512;                    // 110,592
    const int tot2 = 4 * 9 * 9 * 512;                    // 165,888

    transpose_feat<<<NN * HH, 256, 0, stream>>>(feat, featT);
    pack_wB<<<(tot1 + 255) / 256, 256, 0, stream>>>(w1, w1p, CIN, 8, tot1);
    pack_wB<<<(tot2 + 255) / 256, 256, 0, stream>>>(w2, w2p, C1, 9, tot2);
    conv1_mfma<<<NN * HH, 512, 0, stream>>>(featT, w1p, b1, hfeat);
    conv2_fused<<<NN * HH, 512, 0, stream>>>(hfeat, w2p, b2, flow, out);
}